// Round 5
// baseline (325.946 us; speedup 1.0000x reference)
//
#include <hip/hip_runtime.h>
#include <hip/hip_bf16.h>
#include <math.h>

// ---------- helpers ----------
__device__ __forceinline__ unsigned short f2bf(float f) {
    union { float f; unsigned u; } c; c.f = f;
    unsigned r = c.u + 0x7fffu + ((c.u >> 16) & 1u);
    return (unsigned short)(r >> 16);
}
__device__ __forceinline__ float bfu(unsigned short u) {
    union { unsigned x; float f; } c; c.x = ((unsigned)u) << 16; return c.f;
}
__device__ __forceinline__ float gelu_t(float x) {
    float z = x * (1.59576912f + 0.07135481f * x * x);
    return x / (1.0f + __expf(-z));
}

typedef __bf16 bf16x8_t __attribute__((ext_vector_type(8)));
typedef float  f32x4_t  __attribute__((ext_vector_type(4)));

#define AS1 __attribute__((address_space(1)))
#define AS3 __attribute__((address_space(3)))
__device__ __forceinline__ void g2lds16(const void* g, void* l) {
    __builtin_amdgcn_global_load_lds((const AS1 unsigned int*)g, (AS3 unsigned int*)l, 16, 0, 0);
}

// ---------- all weights fp32 -> bf16 in one launch ----------
__global__ void cvt_all(const float* __restrict__ wq, const float* __restrict__ wk,
                        const float* __restrict__ wv, const float* __restrict__ wo,
                        const float* __restrict__ w1, const float* __restrict__ w2,
                        unsigned short* __restrict__ wqkv_b, unsigned short* __restrict__ wo_b,
                        unsigned short* __restrict__ w1_b, unsigned short* __restrict__ w2_b) {
    int i = blockIdx.x * 256 + threadIdx.x;   // float4 units
    const float* src; unsigned short* dst; int base;
    if (i < 16384)       { src = wq; dst = wqkv_b;          base = 0; }
    else if (i < 32768)  { src = wk; dst = wqkv_b + 65536;  base = 16384; }
    else if (i < 49152)  { src = wv; dst = wqkv_b + 131072; base = 32768; }
    else if (i < 65536)  { src = wo; dst = wo_b;            base = 49152; }
    else if (i < 131072) { src = w1; dst = w1_b;            base = 65536; }
    else                 { src = w2; dst = w2_b;            base = 131072; }
    int j = (i - base) * 4;
    float4 v = *(const float4*)(src + j);
    ushort4 o = { f2bf(v.x), f2bf(v.y), f2bf(v.z), f2bf(v.w) };
    *(ushort4*)(dst + j) = o;
}

// ---------- LayerNorm (fp32 in, bf16 out); GATHER fuses shift+window-partition ----------
template<int GATHER>
__global__ void ln_kernel(const float* __restrict__ x, const float* __restrict__ g,
                          const float* __restrict__ b, unsigned short* __restrict__ out) {
    int row  = blockIdx.x * 4 + (threadIdx.x >> 6);
    int lane = threadIdx.x & 63;
    int src;
    if (GATHER) {
        int bb = row >> 12;
        int rem = row & 4095;
        int winid = rem >> 6, tok = rem & 63;
        int wi = winid >> 3, wj = winid & 7;
        int ii = tok >> 3,  jj = tok & 7;
        int hh = (wi * 8 + ii + 4) & 63;     // roll(-4)
        int ww = (wj * 8 + jj + 4) & 63;
        src = (bb << 12) + hh * 64 + ww;
    } else {
        src = row;
    }
    const float4 v = *(const float4*)(x + (size_t)src * 256 + lane * 4);
    float s  = v.x + v.y + v.z + v.w;
    float s2 = v.x*v.x + v.y*v.y + v.z*v.z + v.w*v.w;
    #pragma unroll
    for (int off = 32; off > 0; off >>= 1) {
        s  += __shfl_xor(s,  off, 64);
        s2 += __shfl_xor(s2, off, 64);
    }
    float mean = s * (1.0f / 256.0f);
    float var  = s2 * (1.0f / 256.0f) - mean * mean;
    float rstd = rsqrtf(var + 1e-5f);
    int c0 = lane * 4;
    float4 gg  = *(const float4*)(g + c0);
    float4 bb4 = *(const float4*)(b + c0);
    ushort4 o;
    o.x = f2bf((v.x - mean) * rstd * gg.x + bb4.x);
    o.y = f2bf((v.y - mean) * rstd * gg.y + bb4.y);
    o.z = f2bf((v.z - mean) * rstd * gg.z + bb4.z);
    o.w = f2bf((v.w - mean) * rstd * gg.w + bb4.w);
    *(ushort4*)(out + (size_t)row * 256 + c0) = o;
}

// ---------- tiled MFMA GEMM: C[M,N] = A[M,K] * Bw[N,K]^T + bias ----------
// 128x128 tile, BK=64, monotonic global_load_lds staging (NO address swizzle —
// permuted lane addresses defeat DMA coalescing: R4 doubled FETCH_SIZE).
// MODE 0: bf16   MODE 1: gelu->bf16   MODE 2: window-reverse scatter + fp32 residual -> bf16
template<int MODE, int K>
__global__ __launch_bounds__(256, 4) void gemm_tile(
        const unsigned short* __restrict__ A,
        const unsigned short* __restrict__ Bw,
        const float* __restrict__ bias,
        int M, int N,
        unsigned short* __restrict__ obf,
        const void* __restrict__ addp) {
    __shared__ unsigned short As[128 * 64];
    __shared__ unsigned short Bs[128 * 64];
    const int t = threadIdx.x;
    const int lane = t & 63, wave = t >> 6;
    const int m0 = blockIdx.x * 128, n0 = blockIdx.y * 128;
    const int wm = (wave >> 1) * 64, wn = (wave & 1) * 64;
    const int lr = lane & 15, kg = lane >> 4;

    f32x4_t acc[4][4];
    #pragma unroll
    for (int i = 0; i < 4; ++i)
        #pragma unroll
        for (int j = 0; j < 4; ++j) { acc[i][j][0]=0.f; acc[i][j][1]=0.f; acc[i][j][2]=0.f; acc[i][j][3]=0.f; }

    // staging: call i stages rows i*32..i*32+31 (full 64-col): thread t -> row i*32+(t>>3), chunk t&7
    const int srow = t >> 3;
    const int sck  = (t & 7) * 8;
    const unsigned short* ga = A  + (size_t)(m0 + srow) * K + sck;
    const unsigned short* gb = Bw + (size_t)(n0 + srow) * K + sck;
    unsigned short* la = &As[t * 8];
    unsigned short* lb = &Bs[t * 8];

    #pragma unroll
    for (int k0 = 0; k0 < K; k0 += 64) {
        __syncthreads();
        #pragma unroll
        for (int i = 0; i < 4; ++i) {
            g2lds16(ga + (size_t)(i * 32) * K + k0, la + i * 2048);
            g2lds16(gb + (size_t)(i * 32) * K + k0, lb + i * 2048);
        }
        __syncthreads();
        #pragma unroll
        for (int ks = 0; ks < 64; ks += 32) {
            bf16x8_t af[4], bfr[4];
            #pragma unroll
            for (int i = 0; i < 4; ++i)
                af[i] = *(const bf16x8_t*)&As[(wm + i * 16 + lr) * 64 + ks + kg * 8];
            #pragma unroll
            for (int j = 0; j < 4; ++j)
                bfr[j] = *(const bf16x8_t*)&Bs[(wn + j * 16 + lr) * 64 + ks + kg * 8];
            #pragma unroll
            for (int i = 0; i < 4; ++i)
                #pragma unroll
                for (int j = 0; j < 4; ++j)
                    acc[i][j] = __builtin_amdgcn_mfma_f32_16x16x32_bf16(af[i], bfr[j], acc[i][j], 0, 0, 0);
        }
    }

    #pragma unroll
    for (int i = 0; i < 4; ++i) {
        #pragma unroll
        for (int j = 0; j < 4; ++j) {
            int col = n0 + wn + j * 16 + lr;
            float bv = bias[col];
            #pragma unroll
            for (int e = 0; e < 4; ++e) {
                int row = m0 + wm + i * 16 + kg * 4 + e;
                float v = acc[i][j][e] + bv;
                if (MODE == 0) {
                    obf[(size_t)row * N + col] = f2bf(v);
                } else if (MODE == 1) {
                    obf[(size_t)row * N + col] = f2bf(gelu_t(v));
                } else {
                    int bb = row >> 12;
                    int rem = row & 4095;
                    int winid = rem >> 6, tok = rem & 63;
                    int wi = winid >> 3, wj = winid & 7;
                    int ii = tok >> 3,  jj = tok & 7;
                    int hh = (wi * 8 + ii + 4) & 63;   // roll(+4)
                    int ww = (wj * 8 + jj + 4) & 63;
                    size_t dst = ((size_t)(bb << 12) + hh * 64 + ww) * 256 + col;
                    obf[dst] = f2bf(((const float*)addp)[dst] + v);
                }
            }
        }
    }
}

// ---------- fused LN2 + MLP(up, GELU, down) + residual ----------
// block = 64 rows; Ys = LN2(hidden-tile) in LDS (32 KB); loop 8 n-chunks of 128:
//   gemm1: h = gelu(Ys @ W1c^T + b1c) -> Hs (A-layout round-trip, pad 136)
//   gemm2: acc2 += Hs @ W2c^T   (W1/W2 streamed from global -> L2-resident, 1 MB total)
// epilogue: out = acc2 + b2 + hidden (bf16 residual), fp32.
__global__ __launch_bounds__(256, 3) void mlp_fused(
        const unsigned short* __restrict__ hid,    // [32768,256] bf16
        const float* __restrict__ g2, const float* __restrict__ bb2ln,
        const unsigned short* __restrict__ w1, const float* __restrict__ b1,
        const unsigned short* __restrict__ w2, const float* __restrict__ b2,
        float* __restrict__ out) {
    __shared__ unsigned short Ys[64 * 256];   // 32 KB
    __shared__ unsigned short Hs[64 * 136];   // 17 KB (136*2=272B row stride, 16B-aligned)
    const int t = threadIdx.x;
    const int lane = t & 63, wave = t >> 6;
    const int m0 = blockIdx.x * 64;
    const int lr = lane & 15, kg = lane >> 4;
    const int wm = (wave >> 1) * 32;     // m-half (both gemms)
    const int wn1 = (wave & 1) * 64;     // gemm1 n-half within chunk
    const int wo2 = (wave & 1) * 128;    // gemm2 o-half

    // stage hidden tile (raw bf16): call c: thread t -> row c*8+(t>>5), chunk t&31
    #pragma unroll
    for (int c = 0; c < 8; ++c)
        g2lds16(hid + (size_t)(m0 + c * 8 + (t >> 5)) * 256 + (t & 31) * 8,
                &Ys[c * 2048 + t * 8]);
    __syncthreads();

    // in-place LN2: thread t handles row t>>2, quarter (t&3)*64..+63
    {
        int r = t >> 2, q = t & 3;
        unsigned short* rp = &Ys[r * 256 + q * 64];
        float s = 0.f, s2 = 0.f;
        #pragma unroll
        for (int c8 = 0; c8 < 8; ++c8) {
            bf16x8_t u = *(const bf16x8_t*)(rp + c8 * 8);
            #pragma unroll
            for (int e = 0; e < 8; ++e) {
                float f = (float)u[e];
                s += f; s2 += f * f;
            }
        }
        s  += __shfl_xor(s, 1, 64);  s  += __shfl_xor(s, 2, 64);
        s2 += __shfl_xor(s2, 1, 64); s2 += __shfl_xor(s2, 2, 64);
        float mean = s * (1.0f / 256.0f);
        float var  = s2 * (1.0f / 256.0f) - mean * mean;
        float rstd = rsqrtf(var + 1e-5f);
        #pragma unroll
        for (int c8 = 0; c8 < 8; ++c8) {
            int col = q * 64 + c8 * 8;
            bf16x8_t u = *(const bf16x8_t*)(rp + c8 * 8);
            float4 ga = *(const float4*)(g2 + col),     gb4 = *(const float4*)(g2 + col + 4);
            float4 ba = *(const float4*)(bb2ln + col),  bb4 = *(const float4*)(bb2ln + col + 4);
            unsigned short o[8];
            o[0] = f2bf(((float)u[0] - mean) * rstd * ga.x + ba.x);
            o[1] = f2bf(((float)u[1] - mean) * rstd * ga.y + ba.y);
            o[2] = f2bf(((float)u[2] - mean) * rstd * ga.z + ba.z);
            o[3] = f2bf(((float)u[3] - mean) * rstd * ga.w + ba.w);
            o[4] = f2bf(((float)u[4] - mean) * rstd * gb4.x + bb4.x);
            o[5] = f2bf(((float)u[5] - mean) * rstd * gb4.y + bb4.y);
            o[6] = f2bf(((float)u[6] - mean) * rstd * gb4.z + bb4.z);
            o[7] = f2bf(((float)u[7] - mean) * rstd * gb4.w + bb4.w);
            *(ushort4*)(rp + c8 * 8)     = *(ushort4*)&o[0];
            *(ushort4*)(rp + c8 * 8 + 4) = *(ushort4*)&o[4];
        }
    }
    __syncthreads();

    f32x4_t acc2[2][8];
    #pragma unroll
    for (int i = 0; i < 2; ++i)
        #pragma unroll
        for (int j = 0; j < 8; ++j) { acc2[i][j][0]=0.f; acc2[i][j][1]=0.f; acc2[i][j][2]=0.f; acc2[i][j][3]=0.f; }

    for (int c = 0; c < 8; ++c) {
        const int n0c = c * 128;
        // ---- gemm1: h[wm..+31][wn1..+63] over K=256
        f32x4_t acc1[2][4];
        #pragma unroll
        for (int i = 0; i < 2; ++i)
            #pragma unroll
            for (int j = 0; j < 4; ++j) { acc1[i][j][0]=0.f; acc1[i][j][1]=0.f; acc1[i][j][2]=0.f; acc1[i][j][3]=0.f; }
        #pragma unroll
        for (int kc = 0; kc < 8; ++kc) {
            bf16x8_t af[2], bfr[4];
            #pragma unroll
            for (int i = 0; i < 2; ++i)
                af[i] = *(const bf16x8_t*)&Ys[(wm + i * 16 + lr) * 256 + kc * 32 + kg * 8];
            #pragma unroll
            for (int j = 0; j < 4; ++j)
                bfr[j] = *(const bf16x8_t*)(w1 + (size_t)(n0c + wn1 + j * 16 + lr) * 256 + kc * 32 + kg * 8);
            #pragma unroll
            for (int i = 0; i < 2; ++i)
                #pragma unroll
                for (int j = 0; j < 4; ++j)
                    acc1[i][j] = __builtin_amdgcn_mfma_f32_16x16x32_bf16(af[i], bfr[j], acc1[i][j], 0, 0, 0);
        }
        // gelu -> Hs (C-layout write)
        #pragma unroll
        for (int i = 0; i < 2; ++i)
            #pragma unroll
            for (int j = 0; j < 4; ++j) {
                float bv = b1[n0c + wn1 + j * 16 + lr];
                #pragma unroll
                for (int e = 0; e < 4; ++e) {
                    int rl = wm + i * 16 + kg * 4 + e;
                    Hs[rl * 136 + wn1 + j * 16 + lr] = f2bf(gelu_t(acc1[i][j][e] + bv));
                }
            }
        __syncthreads();
        // ---- gemm2: acc2 += Hs[64x128] @ W2c^T
        #pragma unroll
        for (int kc = 0; kc < 4; ++kc) {
            bf16x8_t af2[2], bf2[8];
            #pragma unroll
            for (int i = 0; i < 2; ++i)
                af2[i] = *(const bf16x8_t*)&Hs[(wm + i * 16 + lr) * 136 + kc * 32 + kg * 8];
            #pragma unroll
            for (int j = 0; j < 8; ++j)
                bf2[j] = *(const bf16x8_t*)(w2 + (size_t)(wo2 + j * 16 + lr) * 1024 + n0c + kc * 32 + kg * 8);
            #pragma unroll
            for (int i = 0; i < 2; ++i)
                #pragma unroll
                for (int j = 0; j < 8; ++j)
                    acc2[i][j] = __builtin_amdgcn_mfma_f32_16x16x32_bf16(af2[i], bf2[j], acc2[i][j], 0, 0, 0);
        }
        __syncthreads();   // protect Hs before next chunk overwrites
    }

    // epilogue: out = acc2 + b2 + residual(bf16)
    #pragma unroll
    for (int i = 0; i < 2; ++i)
        #pragma unroll
        for (int j = 0; j < 8; ++j) {
            int col = wo2 + j * 16 + lr;
            float bv = b2[col];
            #pragma unroll
            for (int e = 0; e < 4; ++e) {
                int row = m0 + wm + i * 16 + kg * 4 + e;
                size_t dst = (size_t)row * 256 + col;
                out[dst] = acc2[i][j][e] + bv + bfu(hid[dst]);
            }
        }
}

// ---------- MFMA attention: 4 waves/block, each wave one (window-batch, head) ----------
#define PR 72
#define VR 72
__global__ void __launch_bounds__(256) attn_mfma(
        const unsigned short* __restrict__ qkv,
        const float* __restrict__ relt,
        unsigned short* __restrict__ ctx) {
    __shared__ float rs[1800];
    __shared__ unsigned short Pl[4][64 * PR];
    __shared__ unsigned short Vt[4][32 * VR];

    int t = threadIdx.x;
    int lane = t & 63, wave = t >> 6;
    for (int i = t; i < 1800; i += 256) rs[i] = relt[i];
    __syncthreads();

    int wh = blockIdx.x * 4 + wave;
    int wg = wh >> 3, h = wh & 7;
    int win = wg & 63;
    int ln = lane & 15, quad = lane >> 4;

    unsigned short* P = &Pl[wave][0];
    unsigned short* V = &Vt[wave][0];
    const unsigned short* base = qkv + (size_t)wg * 64 * 768 + h * 32;

    union BF8 { bf16x8_t v; unsigned short s[8]; };
    {
        const bf16x8_t* vp = (const bf16x8_t*)(base + (size_t)lane * 768 + 512);
        BF8 vv[4];
        #pragma unroll
        for (int c = 0; c < 4; ++c) vv[c].v = vp[c];
        #pragma unroll
        for (int c = 0; c < 4; ++c)
            #pragma unroll
            for (int e = 0; e < 8; ++e)
                V[(c * 8 + e) * VR + lane] = vv[c].s[e];
    }

    bf16x8_t qa[4], kb[4];
    #pragma unroll
    for (int i = 0; i < 4; ++i)
        qa[i] = *(const bf16x8_t*)(base + (size_t)(i * 16 + ln) * 768 + quad * 8);
    #pragma unroll
    for (int j = 0; j < 4; ++j)
        kb[j] = *(const bf16x8_t*)(base + (size_t)(j * 16 + ln) * 768 + 256 + quad * 8);

    f32x4_t acc[4][4];
    #pragma unroll
    for (int i = 0; i < 4; ++i)
        #pragma unroll
        for (int j = 0; j < 4; ++j) { acc[i][j][0]=0.f; acc[i][j][1]=0.f; acc[i][j][2]=0.f; acc[i][j][3]=0.f; }
    #pragma unroll
    for (int i = 0; i < 4; ++i)
        #pragma unroll
        for (int j = 0; j < 4; ++j)
            acc[i][j] = __builtin_amdgcn_mfma_f32_16x16x32_bf16(qa[i], kb[j], acc[i][j], 0, 0, 0);

    const float scale = 0.17677669529663687f;
    int wi = win >> 3, wj = win & 7;
    int mjv = ln & 7;
    int regm[4], mi[4];
    #pragma unroll
    for (int j = 0; j < 4; ++j) {
        mi[j] = j * 2 + (ln >> 3);
        int hm = wi * 8 + mi[j], wm = wj * 8 + mjv;
        regm[j] = (hm < 56 ? 0 : (hm < 60 ? 1 : 2)) * 3 + (wm < 56 ? 0 : (wm < 60 ? 1 : 2));
    }
    float inv[4][4];
    #pragma unroll
    for (int i = 0; i < 4; ++i) {
        #pragma unroll
        for (int e = 0; e < 4; ++e) {
            int q = i * 16 + quad * 4 + e;
            int ti = q >> 3, tj = q & 7;
            int hn = wi * 8 + ti, wn = wj * 8 + tj;
            int regn = (hn < 56 ? 0 : (hn < 60 ? 1 : 2)) * 3 + (wn < 56 ? 0 : (wn < 60 ? 1 : 2));
            float sum = 0.f;
            #pragma unroll
            for (int j = 0; j < 4; ++j) {
                float bv = rs[((ti - mi[j] + 7) * 15 + (tj - mjv + 7)) * 8 + h];
                float s = acc[i][j][e] * scale + bv + (regm[j] != regn ? -100.f : 0.f);
                float p = __expf(s);
                sum += p;
                P[q * PR + j * 16 + ln] = f2bf(p);
            }
            #pragma unroll
            for (int off = 1; off < 16; off <<= 1) sum += __shfl_xor(sum, off, 64);
            inv[i][e] = 1.0f / sum;
        }
    }
    __syncthreads();

    bf16x8_t vb[2][2];
    #pragma unroll
    for (int jd = 0; jd < 2; ++jd)
        #pragma unroll
        for (int kc = 0; kc < 2; ++kc)
            vb[jd][kc] = *(const bf16x8_t*)&V[(jd * 16 + ln) * VR + kc * 32 + quad * 8];
    f32x4_t occ[4][2];
    #pragma unroll
    for (int i = 0; i < 4; ++i)
        #pragma unroll
        for (int jd = 0; jd < 2; ++jd) { occ[i][jd][0]=0.f; occ[i][jd][1]=0.f; occ[i][jd][2]=0.f; occ[i][jd][3]=0.f; }
    #pragma unroll
    for (int i = 0; i < 4; ++i) {
        #pragma unroll
        for (int kc = 0; kc < 2; ++kc) {
            bf16x8_t pf = *(const bf16x8_t*)&P[(i * 16 + ln) * PR + kc * 32 + quad * 8];
            occ[i][0] = __builtin_amdgcn_mfma_f32_16x16x32_bf16(pf, vb[0][kc], occ[i][0], 0, 0, 0);
            occ[i][1] = __builtin_amdgcn_mfma_f32_16x16x32_bf16(pf, vb[1][kc], occ[i][1], 0, 0, 0);
        }
    }

    unsigned short* cbase = ctx + (size_t)wg * 64 * 256 + h * 32;
    #pragma unroll
    for (int i = 0; i < 4; ++i)
        #pragma unroll
        for (int e = 0; e < 4; ++e) {
            int q = i * 16 + quad * 4 + e;
            #pragma unroll
            for (int jd = 0; jd < 2; ++jd)
                cbase[(size_t)q * 256 + jd * 16 + ln] = f2bf(occ[i][jd][e] * inv[i][e]);
        }
}

// ---------- launch ----------
extern "C" void kernel_launch(void* const* d_in, const int* in_sizes, int n_in,
                              void* d_out, int out_size, void* d_ws, size_t ws_size,
                              hipStream_t stream) {
    const float* hs   = (const float*)d_in[0];
    const float* ln1g = (const float*)d_in[1];
    const float* ln1b = (const float*)d_in[2];
    const float* wq   = (const float*)d_in[3];
    const float* bq   = (const float*)d_in[4];
    const float* wk   = (const float*)d_in[5];
    const float* bk   = (const float*)d_in[6];
    const float* wv   = (const float*)d_in[7];
    const float* bv   = (const float*)d_in[8];
    const float* relt = (const float*)d_in[9];
    const float* wo   = (const float*)d_in[10];
    const float* bo   = (const float*)d_in[11];
    const float* ln2g = (const float*)d_in[12];
    const float* ln2b = (const float*)d_in[13];
    const float* w1   = (const float*)d_in[14];
    const float* b1   = (const float*)d_in[15];
    const float* w2   = (const float*)d_in[16];
    const float* b2   = (const float*)d_in[17];
    float* out = (float*)d_out;

    const size_t NTOK = 32768;
    size_t off = 0;
    auto carve = [&](size_t bytes) { void* p = (char*)d_ws + off; off += (bytes + 255) & ~(size_t)255; return p; };
    unsigned short* wqkv_b = (unsigned short*)carve(768ull * 256 * 2);
    unsigned short* wo_b   = (unsigned short*)carve(65536ull * 2);
    unsigned short* w1_b   = (unsigned short*)carve(262144ull * 2);
    unsigned short* w2_b   = (unsigned short*)carve(262144ull * 2);
    float*          bqkv   = (float*)carve(768ull * 4);
    unsigned short* hiddenb= (unsigned short*)carve(NTOK * 256 * 2);  // bf16 residual state
    unsigned short* xw     = (unsigned short*)carve(NTOK * 256 * 2);
    unsigned short* qkvb   = (unsigned short*)carve(NTOK * 768 * 2);  // q|k|v
    unsigned short* cx     = (unsigned short*)carve(NTOK * 256 * 2);

    // 1) weights -> bf16; biases packed [768]
    cvt_all<<<768, 256, 0, stream>>>(wq, wk, wv, wo, w1, w2, wqkv_b, wo_b, w1_b, w2_b);
    hipMemcpyAsync(bqkv,       bq, 256 * 4, hipMemcpyDeviceToDevice, stream);
    hipMemcpyAsync(bqkv + 256, bk, 256 * 4, hipMemcpyDeviceToDevice, stream);
    hipMemcpyAsync(bqkv + 512, bv, 256 * 4, hipMemcpyDeviceToDevice, stream);

    // 2) LN1 + cyclic shift + window partition -> xw (bf16)
    ln_kernel<1><<<8192, 256, 0, stream>>>(hs, ln1g, ln1b, xw);

    // 3) fused QKV projection
    gemm_tile<0, 256><<<dim3(256, 6), 256, 0, stream>>>(xw, wqkv_b, bqkv, 32768, 768, qkvb, nullptr);

    // 4) windowed MFMA attention
    attn_mfma<<<1024, 256, 0, stream>>>(qkvb, relt, cx);

    // 5) out projection + window reverse + unshift + fp32 residual -> hiddenb (bf16)
    gemm_tile<2, 256><<<dim3(256, 2), 256, 0, stream>>>(cx, wo_b, bo, 32768, 256, hiddenb, hs);

    // 6) fused LN2 + MLP + residual -> out (fp32)
    mlp_fused<<<512, 256, 0, stream>>>(hiddenb, ln2g, ln2b, w1_b, b1, w2_b, b2, out);
}

// Round 6
// 268.680 us; speedup vs baseline: 1.2131x; 1.2131x over previous
//
#include <hip/hip_runtime.h>
#include <hip/hip_bf16.h>
#include <math.h>

// ---------- helpers ----------
__device__ __forceinline__ unsigned short f2bf(float f) {
    union { float f; unsigned u; } c; c.f = f;
    unsigned r = c.u + 0x7fffu + ((c.u >> 16) & 1u);
    return (unsigned short)(r >> 16);
}
__device__ __forceinline__ float bfu(unsigned short u) {
    union { unsigned x; float f; } c; c.x = ((unsigned)u) << 16; return c.f;
}
__device__ __forceinline__ float gelu_t(float x) {
    float z = x * (1.59576912f + 0.07135481f * x * x);
    return x / (1.0f + __expf(-z));
}

typedef __bf16 bf16x8_t __attribute__((ext_vector_type(8)));
typedef float  f32x4_t  __attribute__((ext_vector_type(4)));

#define AS1 __attribute__((address_space(1)))
#define AS3 __attribute__((address_space(3)))
__device__ __forceinline__ void g2lds16(const void* g, void* l) {
    __builtin_amdgcn_global_load_lds((const AS1 unsigned int*)g, (AS3 unsigned int*)l, 16, 0, 0);
}

// ---------- all weights fp32 -> bf16 in one launch ----------
__global__ void cvt_all(const float* __restrict__ wq, const float* __restrict__ wk,
                        const float* __restrict__ wv, const float* __restrict__ wo,
                        const float* __restrict__ w1, const float* __restrict__ w2,
                        unsigned short* __restrict__ wqkv_b, unsigned short* __restrict__ wo_b,
                        unsigned short* __restrict__ w1_b, unsigned short* __restrict__ w2_b) {
    int i = blockIdx.x * 256 + threadIdx.x;   // float4 units
    const float* src; unsigned short* dst; int base;
    if (i < 16384)       { src = wq; dst = wqkv_b;          base = 0; }
    else if (i < 32768)  { src = wk; dst = wqkv_b + 65536;  base = 16384; }
    else if (i < 49152)  { src = wv; dst = wqkv_b + 131072; base = 32768; }
    else if (i < 65536)  { src = wo; dst = wo_b;            base = 49152; }
    else if (i < 131072) { src = w1; dst = w1_b;            base = 65536; }
    else                 { src = w2; dst = w2_b;            base = 131072; }
    int j = (i - base) * 4;
    float4 v = *(const float4*)(src + j);
    ushort4 o = { f2bf(v.x), f2bf(v.y), f2bf(v.z), f2bf(v.w) };
    *(ushort4*)(dst + j) = o;
}

// ---------- LayerNorm; GATHER=1 fuses shift+window-partition; BF16IN: input bf16 ----------
template<int GATHER, int BF16IN>
__global__ void ln_kernel(const void* __restrict__ xv, const float* __restrict__ g,
                          const float* __restrict__ b, unsigned short* __restrict__ out) {
    int row  = blockIdx.x * 4 + (threadIdx.x >> 6);
    int lane = threadIdx.x & 63;
    int src;
    if (GATHER) {
        int bb = row >> 12;
        int rem = row & 4095;
        int winid = rem >> 6, tok = rem & 63;
        int wi = winid >> 3, wj = winid & 7;
        int ii = tok >> 3,  jj = tok & 7;
        int hh = (wi * 8 + ii + 4) & 63;     // roll(-4)
        int ww = (wj * 8 + jj + 4) & 63;
        src = (bb << 12) + hh * 64 + ww;
    } else {
        src = row;
    }
    float4 v;
    if (BF16IN) {
        ushort4 u = *(const ushort4*)((const unsigned short*)xv + (size_t)src * 256 + lane * 4);
        v.x = bfu(u.x); v.y = bfu(u.y); v.z = bfu(u.z); v.w = bfu(u.w);
    } else {
        v = *(const float4*)((const float*)xv + (size_t)src * 256 + lane * 4);
    }
    float s  = v.x + v.y + v.z + v.w;
    float s2 = v.x*v.x + v.y*v.y + v.z*v.z + v.w*v.w;
    #pragma unroll
    for (int off = 32; off > 0; off >>= 1) {
        s  += __shfl_xor(s,  off, 64);
        s2 += __shfl_xor(s2, off, 64);
    }
    float mean = s * (1.0f / 256.0f);
    float var  = s2 * (1.0f / 256.0f) - mean * mean;
    float rstd = rsqrtf(var + 1e-5f);
    int c0 = lane * 4;
    float4 gg  = *(const float4*)(g + c0);
    float4 bb4 = *(const float4*)(b + c0);
    ushort4 o;
    o.x = f2bf((v.x - mean) * rstd * gg.x + bb4.x);
    o.y = f2bf((v.y - mean) * rstd * gg.y + bb4.y);
    o.z = f2bf((v.z - mean) * rstd * gg.z + bb4.z);
    o.w = f2bf((v.w - mean) * rstd * gg.w + bb4.w);
    *(ushort4*)(out + (size_t)row * 256 + c0) = o;
}

// ---------- tiled MFMA GEMM: C[M,N] = A[M,K] * Bw[N,K]^T + bias ----------
// 128x128 tile, BK=64, monotonic global_load_lds staging (address swizzle on the
// DMA global side doubles FETCH_SIZE — R4), linear LDS (conflicts benign — R3/R4 A/B).
// MODE 0: bf16   MODE 1: gelu->bf16
// MODE 2: window-reverse scatter + fp32 residual -> bf16
// MODE 3: + bf16 residual -> fp32 out
template<int MODE, int K>
__global__ __launch_bounds__(256, 4) void gemm_tile(
        const unsigned short* __restrict__ A,
        const unsigned short* __restrict__ Bw,
        const float* __restrict__ bias,
        int M, int N,
        unsigned short* __restrict__ obf,
        float* __restrict__ of32,
        const void* __restrict__ addp) {
    __shared__ unsigned short As[128 * 64];
    __shared__ unsigned short Bs[128 * 64];
    const int t = threadIdx.x;
    const int lane = t & 63, wave = t >> 6;
    const int m0 = blockIdx.x * 128, n0 = blockIdx.y * 128;
    const int wm = (wave >> 1) * 64, wn = (wave & 1) * 64;
    const int lr = lane & 15, kg = lane >> 4;

    f32x4_t acc[4][4];
    #pragma unroll
    for (int i = 0; i < 4; ++i)
        #pragma unroll
        for (int j = 0; j < 4; ++j) { acc[i][j][0]=0.f; acc[i][j][1]=0.f; acc[i][j][2]=0.f; acc[i][j][3]=0.f; }

    const int srow = t >> 3;
    const int sck  = (t & 7) * 8;
    const unsigned short* ga = A  + (size_t)(m0 + srow) * K + sck;
    const unsigned short* gb = Bw + (size_t)(n0 + srow) * K + sck;
    unsigned short* la = &As[t * 8];
    unsigned short* lb = &Bs[t * 8];

    #pragma unroll
    for (int k0 = 0; k0 < K; k0 += 64) {
        __syncthreads();
        #pragma unroll
        for (int i = 0; i < 4; ++i) {
            g2lds16(ga + (size_t)(i * 32) * K + k0, la + i * 2048);
            g2lds16(gb + (size_t)(i * 32) * K + k0, lb + i * 2048);
        }
        __syncthreads();
        #pragma unroll
        for (int ks = 0; ks < 64; ks += 32) {
            bf16x8_t af[4], bfr[4];
            #pragma unroll
            for (int i = 0; i < 4; ++i)
                af[i] = *(const bf16x8_t*)&As[(wm + i * 16 + lr) * 64 + ks + kg * 8];
            #pragma unroll
            for (int j = 0; j < 4; ++j)
                bfr[j] = *(const bf16x8_t*)&Bs[(wn + j * 16 + lr) * 64 + ks + kg * 8];
            #pragma unroll
            for (int i = 0; i < 4; ++i)
                #pragma unroll
                for (int j = 0; j < 4; ++j)
                    acc[i][j] = __builtin_amdgcn_mfma_f32_16x16x32_bf16(af[i], bfr[j], acc[i][j], 0, 0, 0);
        }
    }

    #pragma unroll
    for (int i = 0; i < 4; ++i) {
        #pragma unroll
        for (int j = 0; j < 4; ++j) {
            int col = n0 + wn + j * 16 + lr;
            float bv = bias[col];
            #pragma unroll
            for (int e = 0; e < 4; ++e) {
                int row = m0 + wm + i * 16 + kg * 4 + e;
                float v = acc[i][j][e] + bv;
                if (MODE == 0) {
                    obf[(size_t)row * N + col] = f2bf(v);
                } else if (MODE == 1) {
                    obf[(size_t)row * N + col] = f2bf(gelu_t(v));
                } else if (MODE == 2) {
                    int bb = row >> 12;
                    int rem = row & 4095;
                    int winid = rem >> 6, tok = rem & 63;
                    int wi = winid >> 3, wj = winid & 7;
                    int ii = tok >> 3,  jj = tok & 7;
                    int hh = (wi * 8 + ii + 4) & 63;   // roll(+4)
                    int ww = (wj * 8 + jj + 4) & 63;
                    size_t dst = ((size_t)(bb << 12) + hh * 64 + ww) * 256 + col;
                    obf[dst] = f2bf(((const float*)addp)[dst] + v);
                } else {
                    size_t dst = (size_t)row * N + col;
                    of32[dst] = bfu(((const unsigned short*)addp)[dst]) + v;
                }
            }
        }
    }
}

// ---------- MFMA attention: 4 waves/block, each wave one (window-batch, head) ----------
#define PR 72
#define VR 72
__global__ void __launch_bounds__(256) attn_mfma(
        const unsigned short* __restrict__ qkv,
        const float* __restrict__ relt,
        unsigned short* __restrict__ ctx) {
    __shared__ float rs[1800];
    __shared__ unsigned short Pl[4][64 * PR];
    __shared__ unsigned short Vt[4][32 * VR];

    int t = threadIdx.x;
    int lane = t & 63, wave = t >> 6;
    for (int i = t; i < 1800; i += 256) rs[i] = relt[i];
    __syncthreads();

    int wh = blockIdx.x * 4 + wave;
    int wg = wh >> 3, h = wh & 7;
    int win = wg & 63;
    int ln = lane & 15, quad = lane >> 4;

    unsigned short* P = &Pl[wave][0];
    unsigned short* V = &Vt[wave][0];
    const unsigned short* base = qkv + (size_t)wg * 64 * 768 + h * 32;

    union BF8 { bf16x8_t v; unsigned short s[8]; };
    {
        const bf16x8_t* vp = (const bf16x8_t*)(base + (size_t)lane * 768 + 512);
        BF8 vv[4];
        #pragma unroll
        for (int c = 0; c < 4; ++c) vv[c].v = vp[c];
        #pragma unroll
        for (int c = 0; c < 4; ++c)
            #pragma unroll
            for (int e = 0; e < 8; ++e)
                V[(c * 8 + e) * VR + lane] = vv[c].s[e];
    }

    bf16x8_t qa[4], kb[4];
    #pragma unroll
    for (int i = 0; i < 4; ++i)
        qa[i] = *(const bf16x8_t*)(base + (size_t)(i * 16 + ln) * 768 + quad * 8);
    #pragma unroll
    for (int j = 0; j < 4; ++j)
        kb[j] = *(const bf16x8_t*)(base + (size_t)(j * 16 + ln) * 768 + 256 + quad * 8);

    f32x4_t acc[4][4];
    #pragma unroll
    for (int i = 0; i < 4; ++i)
        #pragma unroll
        for (int j = 0; j < 4; ++j) { acc[i][j][0]=0.f; acc[i][j][1]=0.f; acc[i][j][2]=0.f; acc[i][j][3]=0.f; }
    #pragma unroll
    for (int i = 0; i < 4; ++i)
        #pragma unroll
        for (int j = 0; j < 4; ++j)
            acc[i][j] = __builtin_amdgcn_mfma_f32_16x16x32_bf16(qa[i], kb[j], acc[i][j], 0, 0, 0);

    const float scale = 0.17677669529663687f;
    int wi = win >> 3, wj = win & 7;
    int mjv = ln & 7;
    int regm[4], mi[4];
    #pragma unroll
    for (int j = 0; j < 4; ++j) {
        mi[j] = j * 2 + (ln >> 3);
        int hm = wi * 8 + mi[j], wm = wj * 8 + mjv;
        regm[j] = (hm < 56 ? 0 : (hm < 60 ? 1 : 2)) * 3 + (wm < 56 ? 0 : (wm < 60 ? 1 : 2));
    }
    float inv[4][4];
    #pragma unroll
    for (int i = 0; i < 4; ++i) {
        #pragma unroll
        for (int e = 0; e < 4; ++e) {
            int q = i * 16 + quad * 4 + e;
            int ti = q >> 3, tj = q & 7;
            int hn = wi * 8 + ti, wn = wj * 8 + tj;
            int regn = (hn < 56 ? 0 : (hn < 60 ? 1 : 2)) * 3 + (wn < 56 ? 0 : (wn < 60 ? 1 : 2));
            float sum = 0.f;
            #pragma unroll
            for (int j = 0; j < 4; ++j) {
                float bv = rs[((ti - mi[j] + 7) * 15 + (tj - mjv + 7)) * 8 + h];
                float s = acc[i][j][e] * scale + bv + (regm[j] != regn ? -100.f : 0.f);
                float p = __expf(s);
                sum += p;
                P[q * PR + j * 16 + ln] = f2bf(p);
            }
            #pragma unroll
            for (int off = 1; off < 16; off <<= 1) sum += __shfl_xor(sum, off, 64);
            inv[i][e] = 1.0f / sum;
        }
    }
    __syncthreads();

    bf16x8_t vb[2][2];
    #pragma unroll
    for (int jd = 0; jd < 2; ++jd)
        #pragma unroll
        for (int kc = 0; kc < 2; ++kc)
            vb[jd][kc] = *(const bf16x8_t*)&V[(jd * 16 + ln) * VR + kc * 32 + quad * 8];
    f32x4_t occ[4][2];
    #pragma unroll
    for (int i = 0; i < 4; ++i)
        #pragma unroll
        for (int jd = 0; jd < 2; ++jd) { occ[i][jd][0]=0.f; occ[i][jd][1]=0.f; occ[i][jd][2]=0.f; occ[i][jd][3]=0.f; }
    #pragma unroll
    for (int i = 0; i < 4; ++i) {
        #pragma unroll
        for (int kc = 0; kc < 2; ++kc) {
            bf16x8_t pf = *(const bf16x8_t*)&P[(i * 16 + ln) * PR + kc * 32 + quad * 8];
            occ[i][0] = __builtin_amdgcn_mfma_f32_16x16x32_bf16(pf, vb[0][kc], occ[i][0], 0, 0, 0);
            occ[i][1] = __builtin_amdgcn_mfma_f32_16x16x32_bf16(pf, vb[1][kc], occ[i][1], 0, 0, 0);
        }
    }

    unsigned short* cbase = ctx + (size_t)wg * 64 * 256 + h * 32;
    #pragma unroll
    for (int i = 0; i < 4; ++i)
        #pragma unroll
        for (int e = 0; e < 4; ++e) {
            int q = i * 16 + quad * 4 + e;
            #pragma unroll
            for (int jd = 0; jd < 2; ++jd)
                cbase[(size_t)q * 256 + jd * 16 + ln] = f2bf(occ[i][jd][e] * inv[i][e]);
        }
}

// ---------- launch ----------
extern "C" void kernel_launch(void* const* d_in, const int* in_sizes, int n_in,
                              void* d_out, int out_size, void* d_ws, size_t ws_size,
                              hipStream_t stream) {
    const float* hs   = (const float*)d_in[0];
    const float* ln1g = (const float*)d_in[1];
    const float* ln1b = (const float*)d_in[2];
    const float* wq   = (const float*)d_in[3];
    const float* bq   = (const float*)d_in[4];
    const float* wk   = (const float*)d_in[5];
    const float* bk   = (const float*)d_in[6];
    const float* wv   = (const float*)d_in[7];
    const float* bv   = (const float*)d_in[8];
    const float* relt = (const float*)d_in[9];
    const float* wo   = (const float*)d_in[10];
    const float* bo   = (const float*)d_in[11];
    const float* ln2g = (const float*)d_in[12];
    const float* ln2b = (const float*)d_in[13];
    const float* w1   = (const float*)d_in[14];
    const float* b1   = (const float*)d_in[15];
    const float* w2   = (const float*)d_in[16];
    const float* b2   = (const float*)d_in[17];
    float* out = (float*)d_out;

    const size_t NTOK = 32768;
    size_t off = 0;
    auto carve = [&](size_t bytes) { void* p = (char*)d_ws + off; off += (bytes + 255) & ~(size_t)255; return p; };
    unsigned short* wqkv_b = (unsigned short*)carve(768ull * 256 * 2);
    unsigned short* wo_b   = (unsigned short*)carve(65536ull * 2);
    unsigned short* w1_b   = (unsigned short*)carve(262144ull * 2);
    unsigned short* w2_b   = (unsigned short*)carve(262144ull * 2);
    float*          bqkv   = (float*)carve(768ull * 4);
    unsigned short* hiddenb= (unsigned short*)carve(NTOK * 256 * 2);  // bf16 residual state
    unsigned short* xw     = (unsigned short*)carve(NTOK * 256 * 2);  // also LN2 out
    unsigned short* qkvb   = (unsigned short*)carve(NTOK * 768 * 2);  // q|k|v
    unsigned short* cx     = (unsigned short*)carve(NTOK * 256 * 2);
    unsigned short* h1 = qkvb;   // MLP hidden [32768,1024] overlays qkv+cx (64MB)
    unsigned short* yb = xw;

    // 1) weights -> bf16; biases packed [768]
    cvt_all<<<768, 256, 0, stream>>>(wq, wk, wv, wo, w1, w2, wqkv_b, wo_b, w1_b, w2_b);
    hipMemcpyAsync(bqkv,       bq, 256 * 4, hipMemcpyDeviceToDevice, stream);
    hipMemcpyAsync(bqkv + 256, bk, 256 * 4, hipMemcpyDeviceToDevice, stream);
    hipMemcpyAsync(bqkv + 512, bv, 256 * 4, hipMemcpyDeviceToDevice, stream);

    // 2) LN1 + cyclic shift + window partition -> xw (bf16)
    ln_kernel<1, 0><<<8192, 256, 0, stream>>>(hs, ln1g, ln1b, xw);

    // 3) fused QKV projection
    gemm_tile<0, 256><<<dim3(256, 6), 256, 0, stream>>>(xw, wqkv_b, bqkv, 32768, 768, qkvb, nullptr, nullptr);

    // 4) windowed MFMA attention
    attn_mfma<<<1024, 256, 0, stream>>>(qkvb, relt, cx);

    // 5) out projection + window reverse + unshift + fp32 residual -> hiddenb (bf16)
    gemm_tile<2, 256><<<dim3(256, 2), 256, 0, stream>>>(cx, wo_b, bo, 32768, 256, hiddenb, nullptr, hs);

    // 6) LN2 (bf16 in) -> yb
    ln_kernel<0, 1><<<8192, 256, 0, stream>>>(hiddenb, ln2g, ln2b, yb);

    // 7) MLP up + GELU -> h1
    gemm_tile<1, 256><<<dim3(256, 8), 256, 0, stream>>>(yb, w1_b, b1, 32768, 1024, h1, nullptr, nullptr);

    // 8) MLP down + bf16 residual -> out (fp32)
    gemm_tile<3, 1024><<<dim3(256, 2), 256, 0, stream>>>(h1, w2_b, b2, 32768, 256, nullptr, out, hiddenb);
}